// Round 1
// baseline (890.277 us; speedup 1.0000x reference)
//
#include <hip/hip_runtime.h>
#include <math.h>

#define HH 512
#define WW 512
#define HW (HH*WW)          // 262144 = 2^18
#define BATCH 4
#define NCH 18              // simulated channels (18,19 overwritten at end)
#define BHW (BATCH*HW)      // 1048576

// bucket (3 bits) | enough (bit 3)
__global__ __launch_bounds__(256) void bv_bucket_kernel(
    const float* __restrict__ vel, unsigned char* __restrict__ bk)
{
    int idx = blockIdx.x*256 + threadIdx.x;
    if (idx >= BHW) return;
    int b = idx >> 18;
    int rem = idx & (HW-1);
    const float* vb = vel + (size_t)b*2*HW;
    float vy = vb[rem];
    float vx = vb[HW + rem];
    float a2 = vy*vy;          // separate statements: no FMA contraction,
    float b2 = vx*vx;          // match round(vy^2)+round(vx^2)
    float mag = sqrtf(a2 + b2);
    float xx = vx / (mag + 0.001f);
    float af = (float)acos((double)xx);   // correctly-rounded f32 acos
    const float inv2pi = (float)(1.0/(2.0*3.14159265358979323846));
    float raw = inv2pi * af;
    float ang = (vy < 0.0f) ? (1.0f - raw) : raw;
    float t = ang * 8.0f + 0.5f;          // *8 exact, +0.5 one rounding
    int bkt = (int)floorf(t);
    bkt &= 7;                              // mod 8 (t in [0.5, 8.5])
    unsigned char e = (mag > 0.1f) ? (unsigned char)8 : (unsigned char)0;
    bk[idx] = (unsigned char)(bkt | e);
}

__global__ __launch_bounds__(256) void bv_step_kernel(
    const float* __restrict__ Win, int Cin,
    float* __restrict__ Wout, int Cout,
    const unsigned char* __restrict__ bk,
    const float* __restrict__ vel,       // iteration-start velocity (read)
    float* __restrict__ vdelta,          // accumulator (read-modify-write)
    const float* __restrict__ elem_empty,
    int a, int dy, int dx)
{
    int idx = blockIdx.x*256 + threadIdx.x;
    if (idx >= BHW) return;
    int x = idx & (WW-1);
    int y = (idx >> 9) & (HH-1);
    int b = idx >> 18;
    int own = (y<<9) + x;

    const float* inb  = Win  + (size_t)b*Cin*HW;
    float*       outb = Wout + (size_t)b*Cout*HW;

    // sa[i] = (bucket==a) & enough & empty_b[i+d] & ~wall_b[i]
    float sa = 0.0f;
    {
        unsigned char bo = bk[idx];
        int yn = y+dy, xn = x+dx;
        if (((bo & 15) == (a | 8)) && (unsigned)yn < HH && (unsigned)xn < WW) {
            bool emptyn = inb[yn*WW+xn] > 0.5f;       // ch0 at neighbor
            bool wall   = inb[HW + own] > 0.5f;       // ch1 at own
            if (emptyn && !wall) sa = 1.0f;
        }
    }
    // sb[i] = sa[i-d]
    float sb = 0.0f;
    int yp = y-dy, xp = x-dx;
    int popp = (yp<<9) + xp;
    if ((unsigned)yp < HH && (unsigned)xp < WW) {
        unsigned char bp = bk[(b<<18) + popp];
        if ((bp & 15) == (a | 8)) {
            bool emptyn = inb[own] > 0.5f;            // ch0 at (i-d)+d = own
            bool wall   = inb[HW + popp] > 0.5f;      // ch1 at i-d
            if (emptyn && !wall) sb = 1.0f;
        }
    }

    if (sa == 0.0f && sb == 0.0f) {
        // identity: world unchanged; ref's vdelta ops add only +/-0 (|diff|=0)
        const float* pi = inb + own;
        float*       po = outb + own;
        #pragma unroll
        for (int c = 0; c < NCH; ++c) { *po = *pi; pi += HW; po += HW; }
        return;
    }

    const float* pi = inb + own;
    const float* pp = inb + popp;   // only dereferenced when sb==1
    float*       po = outb + own;
    #pragma unroll
    for (int c = 0; c < NCH; ++c) {
        float w  = *pi;
        float wo = (sb != 0.0f) ? *pp : 0.0f;
        float e  = elem_empty[c];
        // exact replication of: w - sa*w - sb*w + sa*e + sb*wo (left-assoc)
        float r = w - sa*w;
        r = r - sb*w;
        r = r + sa*e;
        r = r + sb*wo;
        *po = r;
        pi += HW; pp += HW; po += HW;
    }
    // vdelta: vd = vd - (sa*v)*0.5 ; vd = vd + (sb*vopp)*0.5 (two rounded ops)
    {
        const float* vb = vel    + (size_t)b*2*HW;
        float*       vd = vdelta + (size_t)b*2*HW;
        #pragma unroll
        for (int c = 0; c < 2; ++c) {
            float v  = vb[c*HW + own];
            float vo = (sb != 0.0f) ? vb[c*HW + popp] : 0.0f;
            float d0 = vd[c*HW + own];
            d0 = d0 - (sa*v)*0.5f;
            d0 = d0 + (sb*vo)*0.5f;
            vd[c*HW + own] = d0;
        }
    }
}

// smooth(0.95*v): conv3x3(ones/18, zero-pad) + center*0.5 -> world ch18,19
__global__ __launch_bounds__(256) void bv_smooth_kernel(
    const float* __restrict__ vin, float* __restrict__ dout)
{
    int idx = blockIdx.x*256 + threadIdx.x;   // over BATCH*2*HW
    if (idx >= BATCH*2*HW) return;
    int x = idx & (WW-1);
    int y = (idx >> 9) & (HH-1);
    int c = (idx >> 18) & 1;
    int b = idx >> 19;
    const float* vb = vin + (size_t)(b*2 + c)*HW;
    const float w18 = (float)(1.0/18.0);
    float acc = 0.0f;
    for (int ky = -1; ky <= 1; ++ky) {
        int yy = y + ky;
        if ((unsigned)yy >= HH) continue;
        for (int kx = -1; kx <= 1; ++kx) {
            int xx2 = x + kx;
            if ((unsigned)xx2 >= WW) continue;
            float s = 0.95f * vb[yy*WW + xx2];
            acc += s * w18;
        }
    }
    float sc = 0.95f * vb[y*WW + x];
    float res = acc + sc * 0.5f;
    // world channel 18+c
    dout[((size_t)b*20 + 18 + c)*HW + (size_t)(y<<9) + x] = res;
}

// copy world ch18,19 -> velocity output region (tail of d_out)
__global__ __launch_bounds__(256) void bv_copyvel_kernel(float* __restrict__ dout)
{
    int idx = blockIdx.x*256 + threadIdx.x;   // over BATCH*2*HW
    if (idx >= BATCH*2*HW) return;
    int x = idx & (WW-1);
    int y = (idx >> 9) & (HH-1);
    int c = (idx >> 18) & 1;
    int b = idx >> 19;
    float v = dout[((size_t)b*20 + 18 + c)*HW + (size_t)(y<<9) + x];
    dout[(size_t)BATCH*20*HW + (size_t)idx] = v;
}

extern "C" void kernel_launch(void* const* d_in, const int* in_sizes, int n_in,
                              void* d_out, int out_size, void* d_ws, size_t ws_size,
                              hipStream_t stream)
{
    const float* world_in   = (const float*)d_in[0];
    const float* vel_in     = (const float*)d_in[1];
    const float* elem_empty = (const float*)d_in[2];
    float* out = (float*)d_out;

    // ws layout (<= 85 MB): worldA (18ch) | vel1 | bk
    float* wsA  = (float*)d_ws;                              // 4*18*HW floats
    float* vel1 = wsA + (size_t)BATCH*NCH*HW;                // 4*2*HW floats
    unsigned char* bk = (unsigned char*)(vel1 + (size_t)BATCH*2*HW); // BHW bytes
    // vel2 lives in d_out's velocity tail (unused until the very end)
    float* vel2 = out + (size_t)BATCH*20*HW;                 // 4*2*HW floats

    static const int DY[8] = {-1,-1, 0, 1, 1, 1, 0,-1};
    static const int DX[8] = { 0, 1, 1, 1, 0,-1,-1,-1};

    dim3 blk(256);
    dim3 grd((BHW + 255)/256);
    dim3 g2((BATCH*2*HW + 255)/256);

    // ---- outer iteration 1 ----
    bv_bucket_kernel<<<grd, blk, 0, stream>>>(vel_in, bk);
    hipMemcpyAsync(vel1, vel_in, sizeof(float)*(size_t)BATCH*2*HW,
                   hipMemcpyDeviceToDevice, stream);
    const float* cin = world_in; int Ci = 20;
    for (int a = 0; a < 8; ++a) {
        float* co; int Co;
        if (a & 1) { co = out; Co = 20; } else { co = wsA; Co = NCH; }
        bv_step_kernel<<<grd, blk, 0, stream>>>(cin, Ci, co, Co, bk,
                                                vel_in, vel1, elem_empty,
                                                a, DY[a], DX[a]);
        cin = co; Ci = Co;
    }
    // ---- outer iteration 2 ----
    bv_bucket_kernel<<<grd, blk, 0, stream>>>(vel1, bk);
    hipMemcpyAsync(vel2, vel1, sizeof(float)*(size_t)BATCH*2*HW,
                   hipMemcpyDeviceToDevice, stream);
    for (int a = 0; a < 8; ++a) {
        float* co; int Co;
        if (a & 1) { co = out; Co = 20; } else { co = wsA; Co = NCH; }
        bv_step_kernel<<<grd, blk, 0, stream>>>(cin, Ci, co, Co, bk,
                                                vel1, vel2, elem_empty,
                                                a, DY[a], DX[a]);
        cin = co; Ci = Co;
    }
    // ---- epilogue: world ch0..17 already in d_out (step 15 wrote it) ----
    bv_smooth_kernel<<<g2, blk, 0, stream>>>(vel2, out);   // writes ch18,19
    bv_copyvel_kernel<<<g2, blk, 0, stream>>>(out);        // ch18,19 -> vel tail
}

// Round 2
// 583.860 us; speedup vs baseline: 1.5248x; 1.5248x over previous
//
#include <hip/hip_runtime.h>
#include <math.h>

#define HH 512
#define WW 512
#define HW (HH*WW)          // 262144 = 2^18
#define BATCH 4
#define NCH 18              // simulated channels (18,19 overwritten at end)
#define BHW (BATCH*HW)      // 1048576

// bucket (3 bits) | enough (bit 3)  -- arithmetic identical to round 0 (passed)
__global__ __launch_bounds__(256) void bv_bucket_kernel(
    const float* __restrict__ vel, unsigned char* __restrict__ bk)
{
    int idx = blockIdx.x*256 + threadIdx.x;
    if (idx >= BHW) return;
    int b = idx >> 18;
    int rem = idx & (HW-1);
    const float* vb = vel + (size_t)b*2*HW;
    float vy = vb[rem];
    float vx = vb[HW + rem];
    float a2 = vy*vy;
    float b2 = vx*vx;
    float mag = sqrtf(a2 + b2);
    float xx = vx / (mag + 0.001f);
    float af = (float)acos((double)xx);   // correctly-rounded f32 acos
    const float inv2pi = (float)(1.0/(2.0*3.14159265358979323846));
    float raw = inv2pi * af;
    float ang = (vy < 0.0f) ? (1.0f - raw) : raw;
    float t = ang * 8.0f + 0.5f;
    int bkt = (int)floorf(t);
    bkt &= 7;
    unsigned char e = (mag > 0.1f) ? (unsigned char)8 : (unsigned char)0;
    bk[idx] = (unsigned char)(bkt | e);
}

// 4 pixels / thread, float4 channel traffic, branchless update path
__global__ __launch_bounds__(256) void bv_step_kernel(
    const float* __restrict__ Win, int Cin,
    float* __restrict__ Wout, int Cout,
    const unsigned char* __restrict__ bkall,
    const float* __restrict__ vel,       // iteration-start velocity (read)
    float* __restrict__ vdelta,          // accumulator (read-modify-write)
    const float* __restrict__ elem_empty,
    int a, int dy, int dx)
{
    int t = blockIdx.x*256 + threadIdx.x;       // over BHW/4
    if (t >= BHW/4) return;
    int p = t << 2;                              // base pixel
    int x = p & (WW-1);                          // multiple of 4
    int y = (p >> 9) & (HH-1);
    int b = p >> 18;
    int own = (y<<9) + x;

    const float* inb  = Win  + (size_t)b*Cin*HW;
    float*       outb = Wout + (size_t)b*Cout*HW;
    const unsigned char* bkb = bkall + ((size_t)b<<18);

    const int target = a | 8;

    float4 e0 = *(const float4*)(inb + own);        // ch0 (empty) at own
    float4 w1 = *(const float4*)(inb + HW + own);   // ch1 (wall)  at own
    const float* e0f = (const float*)&e0;
    const float* w1f = (const float*)&w1;

    float sa[4] = {0.f,0.f,0.f,0.f};
    float sb[4] = {0.f,0.f,0.f,0.f};
    int popp[4] = {own, own, own, own};

    // sa[j] = match(own) & enough & empty(own+d) & ~wall(own)
    {
        uchar4 bo = *(const uchar4*)(bkb + own);
        unsigned char bov[4] = {bo.x, bo.y, bo.z, bo.w};
        int yn = y + dy;
        if ((unsigned)yn < HH) {
            const float* r0 = inb + yn*WW;          // ch0, neighbor row
            #pragma unroll
            for (int j = 0; j < 4; ++j) {
                int xn = x + j + dx;
                if ((bov[j] & 15) == target && (unsigned)xn < WW) {
                    if (r0[xn] > 0.5f && !(w1f[j] > 0.5f)) sa[j] = 1.0f;
                }
            }
        }
    }
    // sb[j] = sa evaluated at source cell (own - d)
    {
        int yp = y - dy;
        if ((unsigned)yp < HH) {
            const float* r1 = inb + HW + yp*WW;     // ch1, source row
            #pragma unroll
            for (int j = 0; j < 4; ++j) {
                int xs = x + j - dx;
                if ((unsigned)xs < WW) {
                    int q = yp*WW + xs;
                    if ((bkb[q] & 15) == target &&
                        e0f[j] > 0.5f && !(r1[xs] > 0.5f)) {
                        sb[j] = 1.0f;
                        popp[j] = q;
                    }
                }
            }
        }
    }

    // world update: branchless; inactive lanes get r = w exactly
    #pragma unroll
    for (int c = 0; c < NCH; ++c) {
        const float* pc = inb + (size_t)c*HW;
        float4 w = *(const float4*)(pc + own);
        const float* wf = (const float*)&w;
        float e = elem_empty[c];
        float r[4];
        #pragma unroll
        for (int j = 0; j < 4; ++j) {
            float wj = wf[j];
            float wo = (sb[j] != 0.0f) ? pc[popp[j]] : 0.0f;
            // exact replication of: w - sa*w - sb*w + sa*e + sb*wo (left-assoc)
            float rr = wj - sa[j]*wj;
            rr = rr - sb[j]*wj;
            rr = rr + sa[j]*e;
            rr = rr + sb[j]*wo;
            r[j] = rr;
        }
        *(float4*)(outb + (size_t)c*HW + own) = make_float4(r[0],r[1],r[2],r[3]);
    }

    // vdelta RMW only where active (exec-masked -> no traffic when inactive)
    {
        const float* vb = vel    + (size_t)b*2*HW;
        float*       vd = vdelta + (size_t)b*2*HW;
        #pragma unroll
        for (int j = 0; j < 4; ++j) {
            if (sa[j] != 0.0f || sb[j] != 0.0f) {
                #pragma unroll
                for (int c = 0; c < 2; ++c) {
                    float v  = vb[c*HW + own + j];
                    float vo = (sb[j] != 0.0f) ? vb[c*HW + popp[j]] : 0.0f;
                    float d0 = vd[c*HW + own + j];
                    d0 = d0 - (sa[j]*v)*0.5f;
                    d0 = d0 + (sb[j]*vo)*0.5f;
                    vd[c*HW + own + j] = d0;
                }
            }
        }
    }
}

// smooth(0.95*v): conv3x3(ones/18, zero-pad) + center*0.5 -> world ch18,19
__global__ __launch_bounds__(256) void bv_smooth_kernel(
    const float* __restrict__ vin, float* __restrict__ dout)
{
    int idx = blockIdx.x*256 + threadIdx.x;   // over BATCH*2*HW
    if (idx >= BATCH*2*HW) return;
    int x = idx & (WW-1);
    int y = (idx >> 9) & (HH-1);
    int c = (idx >> 18) & 1;
    int b = idx >> 19;
    const float* vb = vin + (size_t)(b*2 + c)*HW;
    const float w18 = (float)(1.0/18.0);
    float acc = 0.0f;
    for (int ky = -1; ky <= 1; ++ky) {
        int yy = y + ky;
        if ((unsigned)yy >= HH) continue;
        for (int kx = -1; kx <= 1; ++kx) {
            int xx2 = x + kx;
            if ((unsigned)xx2 >= WW) continue;
            float s = 0.95f * vb[yy*WW + xx2];
            acc += s * w18;
        }
    }
    float sc = 0.95f * vb[y*WW + x];
    float res = acc + sc * 0.5f;
    dout[((size_t)b*20 + 18 + c)*HW + (size_t)(y<<9) + x] = res;
}

// copy world ch18,19 -> velocity output region (tail of d_out)
__global__ __launch_bounds__(256) void bv_copyvel_kernel(float* __restrict__ dout)
{
    int idx = blockIdx.x*256 + threadIdx.x;   // over BATCH*2*HW
    if (idx >= BATCH*2*HW) return;
    int x = idx & (WW-1);
    int y = (idx >> 9) & (HH-1);
    int c = (idx >> 18) & 1;
    int b = idx >> 19;
    float v = dout[((size_t)b*20 + 18 + c)*HW + (size_t)(y<<9) + x];
    dout[(size_t)BATCH*20*HW + (size_t)idx] = v;
}

extern "C" void kernel_launch(void* const* d_in, const int* in_sizes, int n_in,
                              void* d_out, int out_size, void* d_ws, size_t ws_size,
                              hipStream_t stream)
{
    const float* world_in   = (const float*)d_in[0];
    const float* vel_in     = (const float*)d_in[1];
    const float* elem_empty = (const float*)d_in[2];
    float* out = (float*)d_out;

    // ws layout (<= 85 MB): worldA (18ch) | vel1 | bk
    float* wsA  = (float*)d_ws;                              // 4*18*HW floats
    float* vel1 = wsA + (size_t)BATCH*NCH*HW;                // 4*2*HW floats
    unsigned char* bk = (unsigned char*)(vel1 + (size_t)BATCH*2*HW); // BHW bytes
    // vel2 lives in d_out's velocity tail (unused until the very end)
    float* vel2 = out + (size_t)BATCH*20*HW;                 // 4*2*HW floats

    static const int DY[8] = {-1,-1, 0, 1, 1, 1, 0,-1};
    static const int DX[8] = { 0, 1, 1, 1, 0,-1,-1,-1};

    dim3 blk(256);
    dim3 grd((BHW + 255)/256);
    dim3 grd4((BHW/4 + 255)/256);
    dim3 g2((BATCH*2*HW + 255)/256);

    // ---- outer iteration 1 ----
    bv_bucket_kernel<<<grd, blk, 0, stream>>>(vel_in, bk);
    hipMemcpyAsync(vel1, vel_in, sizeof(float)*(size_t)BATCH*2*HW,
                   hipMemcpyDeviceToDevice, stream);
    const float* cin = world_in; int Ci = 20;
    for (int a = 0; a < 8; ++a) {
        float* co; int Co;
        if (a & 1) { co = out; Co = 20; } else { co = wsA; Co = NCH; }
        bv_step_kernel<<<grd4, blk, 0, stream>>>(cin, Ci, co, Co, bk,
                                                 vel_in, vel1, elem_empty,
                                                 a, DY[a], DX[a]);
        cin = co; Ci = Co;
    }
    // ---- outer iteration 2 ----
    bv_bucket_kernel<<<grd, blk, 0, stream>>>(vel1, bk);
    hipMemcpyAsync(vel2, vel1, sizeof(float)*(size_t)BATCH*2*HW,
                   hipMemcpyDeviceToDevice, stream);
    for (int a = 0; a < 8; ++a) {
        float* co; int Co;
        if (a & 1) { co = out; Co = 20; } else { co = wsA; Co = NCH; }
        bv_step_kernel<<<grd4, blk, 0, stream>>>(cin, Ci, co, Co, bk,
                                                 vel1, vel2, elem_empty,
                                                 a, DY[a], DX[a]);
        cin = co; Ci = Co;
    }
    // ---- epilogue ----
    bv_smooth_kernel<<<g2, blk, 0, stream>>>(vel2, out);   // writes ch18,19
    bv_copyvel_kernel<<<g2, blk, 0, stream>>>(out);        // ch18,19 -> vel tail
}